// Round 1
// 249.613 us; speedup vs baseline: 1.0195x; 1.0195x over previous
//
#include <hip/hip_runtime.h>
#include <hip/hip_fp16.h>

// GCN encoder: 3x GCNConv (+self-loops, sym deg^-1/2 norm) + ELU + mean-pool.
// N=50000, E=800000, IN=128, HID=64, ZDIM=64, G=64. f32 in/out.
// R4/R5 lessons: no big per-lane arrays; bound unroll of LDS-heavy loops.
// R7: CSR gather. R8: parallel scan. R9: fp16 gathered operands.
// R10: fill unmerged. R11: atomic-free fill. R12: two-stage pool.
// R13: gather2+pool fused -> 261us. R14: lane-vectorized gathers = NEUTRAL
//     (latency-bound). R15: 8 rows in flight -> 252.6us.
// R16: ALGEBRAIC RESTRUCTURE. S(hW) = (Sh)W, so layers 2/3 share ONE
//     64-dim gather g = S*h (128B/edge from a 6.4MB fp16 buffer) instead of
//     gathering the 128-dim mu|sig rows (256B/edge from 12.8MB). GEMMs
//     (g@Wmu, g@Wsig) move AFTER the gather and fuse bias+elu+pool-stage-1
//     in their epilogue (LDS column reduce + boundary atomics). Eliminates
//     the A f32 and CD fp16 intermediates entirely.

#define IN_DIM 128
#define HID 64
#define ZDIM 64
#define N_GRAPHS 64
#define SCAN_B 1024

__device__ __forceinline__ float elu1(float x) {
    return x > 0.f ? x : expm1f(x);
}

// rank[e] = within-dst arrival index; kc[d] ends as deg(d).
__global__ void k_count(const int* __restrict__ dst, int* __restrict__ kc,
                        int* __restrict__ rank, int E) {
    int e = blockIdx.x * blockDim.x + threadIdx.x;
    if (e < E) rank[e] = atomicAdd(&kc[dst[e]], 1);
}

// S1: per-block sum of kc -> bsum[blk]
__global__ __launch_bounds__(SCAN_B) void k_scan1(const int* __restrict__ kc,
                                                  int* __restrict__ bsum, int n) {
    __shared__ int wpart[16];
    int tid = threadIdx.x, lane = tid & 63, w = tid >> 6;
    int i = blockIdx.x * SCAN_B + tid;
    int v = (i < n) ? kc[i] : 0;
#pragma unroll
    for (int d = 1; d < 64; d <<= 1) v += __shfl_xor(v, d, 64);
    if (lane == 0) wpart[w] = v;
    __syncthreads();
    if (tid < 16) {
        int t = wpart[tid];
#pragma unroll
        for (int d = 1; d < 16; d <<= 1) t += __shfl_xor(t, d, 64);
        if (tid == 0) bsum[blockIdx.x] = t;
    }
}

// S3: each block re-scans bsum in-register (nb<=64) for its base, then
// offs[i+1] = inclusive prefix, dinv[i] = 1/sqrt(1+kc[i]).
__global__ __launch_bounds__(SCAN_B) void k_scan3(const int* __restrict__ kc,
                                                  const int* __restrict__ bsum,
                                                  int* __restrict__ offs,
                                                  float* __restrict__ dinv,
                                                  int n, int nb) {
    __shared__ int wsum[16];
    __shared__ int sbase;
    int tid = threadIdx.x, lane = tid & 63, w = tid >> 6;
    if (tid < 64) {  // wave 0: exclusive prefix of bsum at blockIdx.x
        int v = (tid < nb) ? bsum[tid] : 0;
        int s = v;
#pragma unroll
        for (int d = 1; d < 64; d <<= 1) {
            int u = __shfl_up(s, d, 64);
            if (tid >= d) s += u;
        }
        if (tid == blockIdx.x) sbase = s - v;
    }
    int i = blockIdx.x * SCAN_B + tid;
    int v = (i < n) ? kc[i] : 0;
    int s = v;
#pragma unroll
    for (int d = 1; d < 64; d <<= 1) {
        int u = __shfl_up(s, d, 64);
        if (lane >= d) s += u;
    }
    if (lane == 63) wsum[w] = s;
    __syncthreads();
    if (tid < 16) {
        int t = wsum[tid];
#pragma unroll
        for (int d = 1; d < 16; d <<= 1) {
            int u = __shfl_up(t, d, 64);
            if (tid >= d) t += u;
        }
        wsum[tid] = t;
    }
    __syncthreads();
    int base = sbase + ((w == 0) ? 0 : wsum[w - 1]);
    if (i < n) {
        offs[i + 1] = base + s;
        dinv[i] = 1.0f / sqrtf(1.0f + (float)v);
        if (i == 0) offs[0] = 0;
    }
}

// Atomic-free fill: unique slot per edge (offs[dst] + rank).
__global__ void k_fill(const int* __restrict__ src, const int* __restrict__ dst,
                       const int* __restrict__ rank, const int* __restrict__ offs,
                       int* __restrict__ csr, int E) {
    int e = blockIdx.x * blockDim.x + threadIdx.x;
    if (e < E) csr[offs[dst[e]] + rank[e]] = src[e];
}

// ts1h[64-tile] = fp16((x_tile[64x128] @ W[128x64]) * dinv).
__global__ __launch_bounds__(256) void k_mm1(const float* __restrict__ x,
                                             const float* __restrict__ W,
                                             const float* __restrict__ dinv,
                                             __half* __restrict__ ts1h, int n) {
    __shared__ float xs[64 * 68];
    __shared__ float ws[64 * 68];
    const int tid = threadIdx.x;
    const int m0 = blockIdx.x * 64;
    const int j = tid & 15;
    const int i = tid >> 4;

    const float4* x4 = (const float4*)x;
    const float4* W4 = (const float4*)W;

    float4 acc[4];
#pragma unroll
    for (int r = 0; r < 4; ++r) acc[r] = make_float4(0.f, 0.f, 0.f, 0.f);

    for (int kk = 0; kk < IN_DIM; kk += 64) {
        __syncthreads();
        for (int idx = tid; idx < 64 * 16; idx += 256) {
            int row = idx >> 4, c4 = idx & 15;
            float4 v = make_float4(0.f, 0.f, 0.f, 0.f);
            if (m0 + row < n) v = x4[(size_t)(m0 + row) * 32 + (kk >> 2) + c4];
            *(float4*)&xs[row * 68 + 4 * c4] = v;
            *(float4*)&ws[row * 68 + 4 * c4] = W4[(size_t)(kk + row) * 16 + c4];
        }
        __syncthreads();
#pragma unroll 1   // dynamic: bounds LDS-read hoisting / VGPR pressure (R5 lesson)
        for (int k4 = 0; k4 < 16; ++k4) {
            float4 a[4];
#pragma unroll
            for (int r = 0; r < 4; ++r)
                a[r] = *(const float4*)&xs[(4 * i + r) * 68 + 4 * k4];
#pragma unroll
            for (int kc = 0; kc < 4; ++kc) {
                float4 bv = *(const float4*)&ws[(4 * k4 + kc) * 68 + 4 * j];
#pragma unroll
                for (int r = 0; r < 4; ++r) {
                    float av = (&a[r].x)[kc];
                    acc[r].x = fmaf(av, bv.x, acc[r].x);
                    acc[r].y = fmaf(av, bv.y, acc[r].y);
                    acc[r].z = fmaf(av, bv.z, acc[r].z);
                    acc[r].w = fmaf(av, bv.w, acc[r].w);
                }
            }
        }
    }

#pragma unroll
    for (int r = 0; r < 4; ++r) {
        int row = m0 + 4 * i + r;
        if (row < n) {
            float di = dinv[row];
            float4 tv = acc[r];
            __half2* p = (__half2*)&ts1h[(size_t)row * HID + 4 * j];
            p[0] = __floats2half2_rn(tv.x * di, tv.y * di);
            p[1] = __floats2half2_rn(tv.z * di, tv.w * di);
        }
    }
}

// Layer-1 gather + full epilogue: hh[i] = fp16(dinv[i] * elu(dinv[i]*(acc+self) + b1)).
// hh is exactly the gathered operand for layer 2/3's shared gather.
// fp16 rows, f32 accum. Half-wave split (even/odd CSR slots), 4 slots per
// half in flight (8 rows/wave), shfl_xor(32) combine.
__global__ __launch_bounds__(256) void k_gather_hh(const int* __restrict__ off,
                                                   const int* __restrict__ csr,
                                                   const float* __restrict__ dinv,
                                                   const __half* __restrict__ ts,
                                                   const float* __restrict__ b1,
                                                   __half* __restrict__ hh, int n) {
    int node = blockIdx.x * 4 + (threadIdx.x >> 6);
    if (node >= n) return;
    int lane = threadIdx.x & 63;
    int half = lane >> 5, l2 = lane & 31;
    int s0 = off[node], s1 = off[node + 1];
    float2 acc = make_float2(0.f, 0.f);
    int k = s0 + half;
    for (; k + 6 < s1; k += 8) {  // slots k, k+2, k+4, k+6 (this half)
        int a = csr[k], b = csr[k + 2], c = csr[k + 4], d = csr[k + 6];
        float2 fa = __half22float2(*(const __half2*)&ts[(size_t)a * 64 + 2 * l2]);
        float2 fb = __half22float2(*(const __half2*)&ts[(size_t)b * 64 + 2 * l2]);
        float2 fc = __half22float2(*(const __half2*)&ts[(size_t)c * 64 + 2 * l2]);
        float2 fd = __half22float2(*(const __half2*)&ts[(size_t)d * 64 + 2 * l2]);
        acc.x += (fa.x + fb.x) + (fc.x + fd.x);
        acc.y += (fa.y + fb.y) + (fc.y + fd.y);
    }
    for (; k + 2 < s1; k += 4) {
        int a = csr[k], b = csr[k + 2];
        float2 fa = __half22float2(*(const __half2*)&ts[(size_t)a * 64 + 2 * l2]);
        float2 fb = __half22float2(*(const __half2*)&ts[(size_t)b * 64 + 2 * l2]);
        acc.x += fa.x + fb.x;
        acc.y += fa.y + fb.y;
    }
    for (; k < s1; k += 2) {
        int a = csr[k];
        float2 fa = __half22float2(*(const __half2*)&ts[(size_t)a * 64 + 2 * l2]);
        acc.x += fa.x;
        acc.y += fa.y;
    }
    acc.x += __shfl_xor(acc.x, 32, 64);
    acc.y += __shfl_xor(acc.y, 32, 64);
    if (half == 0) {
        float2 self = __half22float2(*(const __half2*)&ts[(size_t)node * 64 + 2 * l2]);
        float di = dinv[node];
        float2 bv = ((const float2*)b1)[l2];
        float ax = (acc.x + self.x) * di + bv.x;
        float ay = (acc.y + self.y) * di + bv.y;
        __half2* p = (__half2*)&hh[(size_t)node * 64 + 2 * l2];
        *p = __floats2half2_rn(elu1(ax) * di, elu1(ay) * di);
    }
}

// Layer-2/3 SHARED gather: g[i] = dinv[i]*(acc + hh[i]) = row i of S*h (f32).
__global__ __launch_bounds__(256) void k_gather_g(const int* __restrict__ off,
                                                  const int* __restrict__ csr,
                                                  const float* __restrict__ dinv,
                                                  const __half* __restrict__ hh,
                                                  float* __restrict__ g, int n) {
    int node = blockIdx.x * 4 + (threadIdx.x >> 6);
    if (node >= n) return;
    int lane = threadIdx.x & 63;
    int half = lane >> 5, l2 = lane & 31;
    int s0 = off[node], s1 = off[node + 1];
    float2 acc = make_float2(0.f, 0.f);
    int k = s0 + half;
    for (; k + 6 < s1; k += 8) {
        int a = csr[k], b = csr[k + 2], c = csr[k + 4], d = csr[k + 6];
        float2 fa = __half22float2(*(const __half2*)&hh[(size_t)a * 64 + 2 * l2]);
        float2 fb = __half22float2(*(const __half2*)&hh[(size_t)b * 64 + 2 * l2]);
        float2 fc = __half22float2(*(const __half2*)&hh[(size_t)c * 64 + 2 * l2]);
        float2 fd = __half22float2(*(const __half2*)&hh[(size_t)d * 64 + 2 * l2]);
        acc.x += (fa.x + fb.x) + (fc.x + fd.x);
        acc.y += (fa.y + fb.y) + (fc.y + fd.y);
    }
    for (; k + 2 < s1; k += 4) {
        int a = csr[k], b = csr[k + 2];
        float2 fa = __half22float2(*(const __half2*)&hh[(size_t)a * 64 + 2 * l2]);
        float2 fb = __half22float2(*(const __half2*)&hh[(size_t)b * 64 + 2 * l2]);
        acc.x += fa.x + fb.x;
        acc.y += fa.y + fb.y;
    }
    for (; k < s1; k += 2) {
        int a = csr[k];
        float2 fa = __half22float2(*(const __half2*)&hh[(size_t)a * 64 + 2 * l2]);
        acc.x += fa.x;
        acc.y += fa.y;
    }
    acc.x += __shfl_xor(acc.x, 32, 64);
    acc.y += __shfl_xor(acc.y, 32, 64);
    if (half == 0) {
        float2 self = __half22float2(*(const __half2*)&hh[(size_t)node * 64 + 2 * l2]);
        float di = dinv[node];
        *(float2*)&g[(size_t)node * 64 + 2 * l2] =
            make_float2((acc.x + self.x) * di, (acc.y + self.y) * di);
    }
}

// mu|sig GEMM + bias + elu + pool stage-1.
// P[row][0..63] = elu(g@Wmu + bmu), P[row][64..127] = elu(g@Wsig + bsig),
// staged in LDS (reusing wc) then column-reduced per graph segment with
// boundary-flush atomics into sums (mu at [0,4096), sig at [4096,8192)).
__global__ __launch_bounds__(256) void k_mm_pool(const float* __restrict__ g,
                                                 const float* __restrict__ Wmu,
                                                 const float* __restrict__ Wsig,
                                                 const float* __restrict__ bmu,
                                                 const float* __restrict__ bsig,
                                                 const int* __restrict__ batch,
                                                 float* __restrict__ sums, int n) {
    __shared__ float hs[64 * 68];
    __shared__ float wc[64 * 132];  // [k][0..63]=Wmu, [k][64..127]=Wsig; later P
    __shared__ int bs[64];
    const int tid = threadIdx.x;
    const int m0 = blockIdx.x * 64;
    const int j = tid & 15;
    const int i = tid >> 4;

    const float4* g4 = (const float4*)g;
    const float4* Wm4 = (const float4*)Wmu;
    const float4* Ws4 = (const float4*)Wsig;
    for (int idx = tid; idx < 64 * 16; idx += 256) {
        int row = idx >> 4, c4 = idx & 15;
        float4 v = make_float4(0.f, 0.f, 0.f, 0.f);
        if (m0 + row < n) v = g4[(size_t)(m0 + row) * 16 + c4];
        *(float4*)&hs[row * 68 + 4 * c4] = v;
        *(float4*)&wc[row * 132 + 4 * c4] = Wm4[(size_t)row * 16 + c4];
        *(float4*)&wc[row * 132 + 64 + 4 * c4] = Ws4[(size_t)row * 16 + c4];
    }
    if (tid < 64) bs[tid] = (m0 + tid < n) ? batch[m0 + tid] : -1;
    __syncthreads();

    float4 accm[4], accs[4];
#pragma unroll
    for (int r = 0; r < 4; ++r) {
        accm[r] = make_float4(0.f, 0.f, 0.f, 0.f);
        accs[r] = make_float4(0.f, 0.f, 0.f, 0.f);
    }

#pragma unroll 1   // dynamic: bounds LDS-read hoisting / VGPR pressure (R5 lesson)
    for (int k4 = 0; k4 < 16; ++k4) {
        float4 a[4];
#pragma unroll
        for (int r = 0; r < 4; ++r)
            a[r] = *(const float4*)&hs[(4 * i + r) * 68 + 4 * k4];
#pragma unroll
        for (int kc = 0; kc < 4; ++kc) {
            float4 bm = *(const float4*)&wc[(4 * k4 + kc) * 132 + 4 * j];
            float4 bsv = *(const float4*)&wc[(4 * k4 + kc) * 132 + 64 + 4 * j];
#pragma unroll
            for (int r = 0; r < 4; ++r) {
                float av = (&a[r].x)[kc];
                accm[r].x = fmaf(av, bm.x, accm[r].x);
                accm[r].y = fmaf(av, bm.y, accm[r].y);
                accm[r].z = fmaf(av, bm.z, accm[r].z);
                accm[r].w = fmaf(av, bm.w, accm[r].w);
                accs[r].x = fmaf(av, bsv.x, accs[r].x);
                accs[r].y = fmaf(av, bsv.y, accs[r].y);
                accs[r].z = fmaf(av, bsv.z, accs[r].z);
                accs[r].w = fmaf(av, bsv.w, accs[r].w);
            }
        }
    }

    float4 bm = ((const float4*)bmu)[j];
    float4 bg = ((const float4*)bsig)[j];
    __syncthreads();  // all weight reads done before overwriting wc with P

#pragma unroll
    for (int r = 0; r < 4; ++r) {
        int row = 4 * i + r;
        float4 m = accm[r], s = accs[r];
        m.x = elu1(m.x + bm.x);
        m.y = elu1(m.y + bm.y);
        m.z = elu1(m.z + bm.z);
        m.w = elu1(m.w + bm.w);
        s.x = elu1(s.x + bg.x);
        s.y = elu1(s.y + bg.y);
        s.z = elu1(s.z + bg.z);
        s.w = elu1(s.w + bg.w);
        *(float4*)&wc[row * 132 + 4 * j] = m;
        *(float4*)&wc[row * 132 + 64 + 4 * j] = s;
    }
    __syncthreads();

    // Pool: thread (d, seg) reduces column d over rows [seg*32, seg*32+32),
    // flushing at graph boundaries (batch sorted).
    int d = tid & 127, seg = tid >> 7;
    int base = (d < 64) ? d : (64 * 64 - 64 + d);  // mu: g*64+d, sig: 4096+g*64+(d-64)
    float acc = 0.f;
    int gcur = -1;
    int r0 = seg * 32;
    for (int r = r0; r < r0 + 32; ++r) {
        int gb = bs[r];
        if (gb < 0) break;
        float v = wc[r * 132 + d];
        if (gb != gcur) {
            if (gcur >= 0) atomicAdd(&sums[base + gcur * 64], acc);
            acc = 0.f;
            gcur = gb;
        }
        acc += v;
    }
    if (gcur >= 0) atomicAdd(&sums[base + gcur * 64], acc);
}

// Pool stage 2: one thread per output element; cnt via binary search.
__global__ void k_pool_final(const float* __restrict__ sums,
                             const int* __restrict__ batch,
                             float* __restrict__ out, int n) {
    int i = blockIdx.x * blockDim.x + threadIdx.x;
    if (i >= 2 * N_GRAPHS * ZDIM) return;
    int g = (i >> 6) & 63;
    int lo = 0, hi = n;
    while (lo < hi) { int m = (lo + hi) >> 1; if (batch[m] < g) lo = m + 1; else hi = m; }
    int s = lo;
    lo = s; hi = n;
    while (lo < hi) { int m = (lo + hi) >> 1; if (batch[m] < g + 1) lo = m + 1; else hi = m; }
    float c = fmaxf((float)(lo - s), 1.0f);
    out[i] = sums[i] / c;
}

extern "C" void kernel_launch(void* const* d_in, const int* in_sizes, int n_in,
                              void* d_out, int out_size, void* d_ws, size_t ws_size,
                              hipStream_t stream) {
    const float* x    = (const float*)d_in[0];
    const int*   ei   = (const int*)d_in[1];
    const int*   batch= (const int*)d_in[2];
    // d_in[3] = num_graphs (scalar, known 64)
    const float* W1   = (const float*)d_in[4];
    const float* b1   = (const float*)d_in[5];
    const float* Wmu  = (const float*)d_in[6];
    const float* bmu  = (const float*)d_in[7];
    const float* Wsig = (const float*)d_in[8];
    const float* bsig = (const float*)d_in[9];
    float* out = (float*)d_out;

    const int n = in_sizes[0] / IN_DIM;   // 50000
    const int E = in_sizes[1] / 2;        // 800000
    const int* src = ei;
    const int* dst = ei + E;
    const int NSB = (n + SCAN_B - 1) / SCAN_B;  // scan blocks (49)

    float* ws = (float*)d_ws;
    size_t off_w = 0;
    int*   kc   = (int*)(ws + off_w); off_w += 50048;
    float* sums = ws + off_w; off_w += 8192;   // contiguous with kc: one memset
    float* dinv = ws + off_w; off_w += 50048;
    int*   offs = (int*)(ws + off_w); off_w += 50056;
    int*   bsum = (int*)(ws + off_w); off_w += 64;
    int*   rank = (int*)(ws + off_w); off_w += 800000;
    int*   csr  = (int*)(ws + off_w); off_w += 800000;
    off_w = (off_w + 15) & ~(size_t)15;
    const size_t BIG = (size_t)n * 64;
    __half* ts1h = (__half*)(ws + off_w); off_w += BIG / 2;  // fp16 (x@W1)*dinv
    __half* hh   = (__half*)(ws + off_w); off_w += BIG / 2;  // fp16 dinv*elu(layer1)
    float*  gbuf = ws + off_w; off_w += BIG;                 // f32 g = S*h

    const int gE  = (E + 255) / 256;
    const int gNW = (n + 3) / 4;      // one wave per node
    const int NB  = (n + 63) / 64;    // 64-node GEMM tiles

    // CSR build + normalization (kc+sums zeroed in ONE contiguous memset)
    hipMemsetAsync(kc, 0, (50048 + 8192) * sizeof(int), stream);
    k_count<<<gE, 256, 0, stream>>>(dst, kc, rank, E);
    k_scan1<<<NSB, SCAN_B, 0, stream>>>(kc, bsum, n);
    k_scan3<<<NSB, SCAN_B, 0, stream>>>(kc, bsum, offs, dinv, n, NSB);
    k_fill<<<gE, 256, 0, stream>>>(src, dst, rank, offs, csr, E);

    // layer 1: ts1h = fp16((x@W1)*dinv); hh = fp16(dinv*elu(S(xW1)+b1))
    k_mm1<<<NB, 256, 0, stream>>>(x, W1, dinv, ts1h, n);
    k_gather_hh<<<gNW, 256, 0, stream>>>(offs, csr, dinv, ts1h, b1, hh, n);

    // layers 2/3 shared gather: g = S*h (f32)
    k_gather_g<<<gNW, 256, 0, stream>>>(offs, csr, dinv, hh, gbuf, n);

    // mu|sig GEMM + bias + elu + fused pool stage-1
    k_mm_pool<<<NB, 256, 0, stream>>>(gbuf, Wmu, Wsig, bmu, bsig, batch, sums, n);
    k_pool_final<<<(2 * N_GRAPHS * ZDIM + 255) / 256, 256, 0, stream>>>(sums, batch, out, n);
}

// Round 2
// 238.110 us; speedup vs baseline: 1.0687x; 1.0483x over previous
//
#include <hip/hip_runtime.h>
#include <hip/hip_fp16.h>

// GCN encoder: 3x GCNConv (+self-loops, sym deg^-1/2 norm) + ELU + mean-pool.
// N=50000, E=800000, IN=128, HID=64, ZDIM=64, G=64. f32 in/out.
// R7: CSR gather. R8: parallel scan. R9: fp16 gathered operands.
// R11: atomic-free fill. R12/13: fused pool. R15: 8 rows in flight -> 252.6.
// R16: algebraic restructure S(hW)=(Sh)W -> one shared 64-dim gather for
//     layers 2/3, GEMM+pool fused after. 249.6us. Delta small => gathers are
//     LATENCY-bound, not byte-bound (R14 model confirmed).
// R17: MLP-oriented gather decomposition. lane=(group g=lane>>3, chunk
//     sub=lane&7); each group owns a row, each lane a 16B dwordx4 chunk.
//     4 index loads issued up-front, 32 rows in flight/wave (4x R15).
//     Clamped slots alias the last row's line (L1 hit, no over-fetch).
//     Cross-group combine = 3 shfl_xor rounds, no LDS.

#define IN_DIM 128
#define HID 64
#define ZDIM 64
#define N_GRAPHS 64
#define SCAN_B 1024

__device__ __forceinline__ float elu1(float x) {
    return x > 0.f ? x : expm1f(x);
}

// Accumulate 8 fp16 (held in a float4 raw register) with mask MV into acc[8].
#define ACC8(RV, MV) do { \
    const __half2* _hp = (const __half2*)&(RV); \
    float2 _f0 = __half22float2(_hp[0]); \
    float2 _f1 = __half22float2(_hp[1]); \
    float2 _f2 = __half22float2(_hp[2]); \
    float2 _f3 = __half22float2(_hp[3]); \
    acc[0] = fmaf((MV), _f0.x, acc[0]); \
    acc[1] = fmaf((MV), _f0.y, acc[1]); \
    acc[2] = fmaf((MV), _f1.x, acc[2]); \
    acc[3] = fmaf((MV), _f1.y, acc[3]); \
    acc[4] = fmaf((MV), _f2.x, acc[4]); \
    acc[5] = fmaf((MV), _f2.y, acc[5]); \
    acc[6] = fmaf((MV), _f3.x, acc[6]); \
    acc[7] = fmaf((MV), _f3.y, acc[7]); \
  } while (0)

// rank[e] = within-dst arrival index; kc[d] ends as deg(d).
__global__ void k_count(const int* __restrict__ dst, int* __restrict__ kc,
                        int* __restrict__ rank, int E) {
    int e = blockIdx.x * blockDim.x + threadIdx.x;
    if (e < E) rank[e] = atomicAdd(&kc[dst[e]], 1);
}

// S1: per-block sum of kc -> bsum[blk]
__global__ __launch_bounds__(SCAN_B) void k_scan1(const int* __restrict__ kc,
                                                  int* __restrict__ bsum, int n) {
    __shared__ int wpart[16];
    int tid = threadIdx.x, lane = tid & 63, w = tid >> 6;
    int i = blockIdx.x * SCAN_B + tid;
    int v = (i < n) ? kc[i] : 0;
#pragma unroll
    for (int d = 1; d < 64; d <<= 1) v += __shfl_xor(v, d, 64);
    if (lane == 0) wpart[w] = v;
    __syncthreads();
    if (tid < 16) {
        int t = wpart[tid];
#pragma unroll
        for (int d = 1; d < 16; d <<= 1) t += __shfl_xor(t, d, 64);
        if (tid == 0) bsum[blockIdx.x] = t;
    }
}

// S3: each block re-scans bsum in-register (nb<=64) for its base, then
// offs[i+1] = inclusive prefix, dinv[i] = 1/sqrt(1+kc[i]).
__global__ __launch_bounds__(SCAN_B) void k_scan3(const int* __restrict__ kc,
                                                  const int* __restrict__ bsum,
                                                  int* __restrict__ offs,
                                                  float* __restrict__ dinv,
                                                  int n, int nb) {
    __shared__ int wsum[16];
    __shared__ int sbase;
    int tid = threadIdx.x, lane = tid & 63, w = tid >> 6;
    if (tid < 64) {  // wave 0: exclusive prefix of bsum at blockIdx.x
        int v = (tid < nb) ? bsum[tid] : 0;
        int s = v;
#pragma unroll
        for (int d = 1; d < 64; d <<= 1) {
            int u = __shfl_up(s, d, 64);
            if (tid >= d) s += u;
        }
        if (tid == blockIdx.x) sbase = s - v;
    }
    int i = blockIdx.x * SCAN_B + tid;
    int v = (i < n) ? kc[i] : 0;
    int s = v;
#pragma unroll
    for (int d = 1; d < 64; d <<= 1) {
        int u = __shfl_up(s, d, 64);
        if (lane >= d) s += u;
    }
    if (lane == 63) wsum[w] = s;
    __syncthreads();
    if (tid < 16) {
        int t = wsum[tid];
#pragma unroll
        for (int d = 1; d < 16; d <<= 1) {
            int u = __shfl_up(t, d, 64);
            if (tid >= d) t += u;
        }
        wsum[tid] = t;
    }
    __syncthreads();
    int base = sbase + ((w == 0) ? 0 : wsum[w - 1]);
    if (i < n) {
        offs[i + 1] = base + s;
        dinv[i] = 1.0f / sqrtf(1.0f + (float)v);
        if (i == 0) offs[0] = 0;
    }
}

// Atomic-free fill: unique slot per edge (offs[dst] + rank).
__global__ void k_fill(const int* __restrict__ src, const int* __restrict__ dst,
                       const int* __restrict__ rank, const int* __restrict__ offs,
                       int* __restrict__ csr, int E) {
    int e = blockIdx.x * blockDim.x + threadIdx.x;
    if (e < E) csr[offs[dst[e]] + rank[e]] = src[e];
}

// ts1h[64-tile] = fp16((x_tile[64x128] @ W[128x64]) * dinv).
__global__ __launch_bounds__(256) void k_mm1(const float* __restrict__ x,
                                             const float* __restrict__ W,
                                             const float* __restrict__ dinv,
                                             __half* __restrict__ ts1h, int n) {
    __shared__ float xs[64 * 68];
    __shared__ float ws[64 * 68];
    const int tid = threadIdx.x;
    const int m0 = blockIdx.x * 64;
    const int j = tid & 15;
    const int i = tid >> 4;

    const float4* x4 = (const float4*)x;
    const float4* W4 = (const float4*)W;

    float4 acc[4];
#pragma unroll
    for (int r = 0; r < 4; ++r) acc[r] = make_float4(0.f, 0.f, 0.f, 0.f);

    for (int kk = 0; kk < IN_DIM; kk += 64) {
        __syncthreads();
        for (int idx = tid; idx < 64 * 16; idx += 256) {
            int row = idx >> 4, c4 = idx & 15;
            float4 v = make_float4(0.f, 0.f, 0.f, 0.f);
            if (m0 + row < n) v = x4[(size_t)(m0 + row) * 32 + (kk >> 2) + c4];
            *(float4*)&xs[row * 68 + 4 * c4] = v;
            *(float4*)&ws[row * 68 + 4 * c4] = W4[(size_t)(kk + row) * 16 + c4];
        }
        __syncthreads();
#pragma unroll 1   // dynamic: bounds LDS-read hoisting / VGPR pressure (R5 lesson)
        for (int k4 = 0; k4 < 16; ++k4) {
            float4 a[4];
#pragma unroll
            for (int r = 0; r < 4; ++r)
                a[r] = *(const float4*)&xs[(4 * i + r) * 68 + 4 * k4];
#pragma unroll
            for (int kc = 0; kc < 4; ++kc) {
                float4 bv = *(const float4*)&ws[(4 * k4 + kc) * 68 + 4 * j];
#pragma unroll
                for (int r = 0; r < 4; ++r) {
                    float av = (&a[r].x)[kc];
                    acc[r].x = fmaf(av, bv.x, acc[r].x);
                    acc[r].y = fmaf(av, bv.y, acc[r].y);
                    acc[r].z = fmaf(av, bv.z, acc[r].z);
                    acc[r].w = fmaf(av, bv.w, acc[r].w);
                }
            }
        }
    }

#pragma unroll
    for (int r = 0; r < 4; ++r) {
        int row = m0 + 4 * i + r;
        if (row < n) {
            float di = dinv[row];
            float4 tv = acc[r];
            __half2* p = (__half2*)&ts1h[(size_t)row * HID + 4 * j];
            p[0] = __floats2half2_rn(tv.x * di, tv.y * di);
            p[1] = __floats2half2_rn(tv.z * di, tv.w * di);
        }
    }
}

// Layer-1 gather + epilogue: hh[i] = fp16(dinv * elu(dinv*(sum+self) + b1)).
// Wave = node. group g=lane>>3 owns a row, chunk sub=lane&7 owns 16B of it.
// 4 preloaded batches = 32 rows in flight; clamped slots alias last row's
// line (L1 hit). Tail loop for deg>32 (P~1e-4). 3x shfl_xor group combine.
__global__ __launch_bounds__(256) void k_gather_hh(const int* __restrict__ off,
                                                   const int* __restrict__ csr,
                                                   const float* __restrict__ dinv,
                                                   const __half* __restrict__ ts,
                                                   const float* __restrict__ b1,
                                                   __half* __restrict__ hh, int n) {
    int node = blockIdx.x * 4 + (threadIdx.x >> 6);
    if (node >= n) return;
    int lane = threadIdx.x & 63;
    int g = lane >> 3, sub = lane & 7;
    int s0 = off[node], s1 = off[node + 1];
    float acc[8];
#pragma unroll
    for (int j = 0; j < 8; ++j) acc[j] = 0.f;

    if (s1 > s0) {
        int last = s1 - 1;
        int p0 = s0 + g, p1 = p0 + 8, p2 = p0 + 16, p3 = p0 + 24;
        int i0 = csr[p0 < s1 ? p0 : last];
        int i1 = csr[p1 < s1 ? p1 : last];
        int i2 = csr[p2 < s1 ? p2 : last];
        int i3 = csr[p3 < s1 ? p3 : last];
        float4 r0 = *(const float4*)&ts[(size_t)i0 * 64 + sub * 8];
        float4 r1 = *(const float4*)&ts[(size_t)i1 * 64 + sub * 8];
        float4 r2 = *(const float4*)&ts[(size_t)i2 * 64 + sub * 8];
        float4 r3 = *(const float4*)&ts[(size_t)i3 * 64 + sub * 8];
        float m0 = (p0 < s1) ? 1.f : 0.f;
        float m1 = (p1 < s1) ? 1.f : 0.f;
        float m2 = (p2 < s1) ? 1.f : 0.f;
        float m3 = (p3 < s1) ? 1.f : 0.f;
        ACC8(r0, m0);
        ACC8(r1, m1);
        ACC8(r2, m2);
        ACC8(r3, m3);
        for (int k = s0 + 32 + g; k < s1; k += 8) {  // rare (deg>32)
            int iv = csr[k];
            float4 rv = *(const float4*)&ts[(size_t)iv * 64 + sub * 8];
            ACC8(rv, 1.f);
        }
    }

#pragma unroll
    for (int j = 0; j < 8; ++j) {
        acc[j] += __shfl_xor(acc[j], 8, 64);
        acc[j] += __shfl_xor(acc[j], 16, 64);
        acc[j] += __shfl_xor(acc[j], 32, 64);
    }

    if (g == 0) {
        float4 sr = *(const float4*)&ts[(size_t)node * 64 + sub * 8];
        const __half2* sh = (const __half2*)&sr;
        float di = dinv[node];
        const float4* b4 = (const float4*)b1;
        float4 ba = b4[sub * 2], bb = b4[sub * 2 + 1];
        float2 f0 = __half22float2(sh[0]);
        float2 f1 = __half22float2(sh[1]);
        float2 f2 = __half22float2(sh[2]);
        float2 f3 = __half22float2(sh[3]);
        float e0 = elu1((acc[0] + f0.x) * di + ba.x) * di;
        float e1 = elu1((acc[1] + f0.y) * di + ba.y) * di;
        float e2 = elu1((acc[2] + f1.x) * di + ba.z) * di;
        float e3 = elu1((acc[3] + f1.y) * di + ba.w) * di;
        float e4 = elu1((acc[4] + f2.x) * di + bb.x) * di;
        float e5 = elu1((acc[5] + f2.y) * di + bb.y) * di;
        float e6 = elu1((acc[6] + f3.x) * di + bb.z) * di;
        float e7 = elu1((acc[7] + f3.y) * di + bb.w) * di;
        float4 outv;
        __half2* op = (__half2*)&outv;
        op[0] = __floats2half2_rn(e0, e1);
        op[1] = __floats2half2_rn(e2, e3);
        op[2] = __floats2half2_rn(e4, e5);
        op[3] = __floats2half2_rn(e6, e7);
        *(float4*)&hh[(size_t)node * 64 + sub * 8] = outv;
    }
}

// Layer-2/3 SHARED gather: g[i] = dinv[i]*(sum + hh[i]) = row i of S*h (f32).
// Same MLP decomposition as k_gather_hh.
__global__ __launch_bounds__(256) void k_gather_g(const int* __restrict__ off,
                                                  const int* __restrict__ csr,
                                                  const float* __restrict__ dinv,
                                                  const __half* __restrict__ hh,
                                                  float* __restrict__ gout, int n) {
    int node = blockIdx.x * 4 + (threadIdx.x >> 6);
    if (node >= n) return;
    int lane = threadIdx.x & 63;
    int g = lane >> 3, sub = lane & 7;
    int s0 = off[node], s1 = off[node + 1];
    float acc[8];
#pragma unroll
    for (int j = 0; j < 8; ++j) acc[j] = 0.f;

    if (s1 > s0) {
        int last = s1 - 1;
        int p0 = s0 + g, p1 = p0 + 8, p2 = p0 + 16, p3 = p0 + 24;
        int i0 = csr[p0 < s1 ? p0 : last];
        int i1 = csr[p1 < s1 ? p1 : last];
        int i2 = csr[p2 < s1 ? p2 : last];
        int i3 = csr[p3 < s1 ? p3 : last];
        float4 r0 = *(const float4*)&hh[(size_t)i0 * 64 + sub * 8];
        float4 r1 = *(const float4*)&hh[(size_t)i1 * 64 + sub * 8];
        float4 r2 = *(const float4*)&hh[(size_t)i2 * 64 + sub * 8];
        float4 r3 = *(const float4*)&hh[(size_t)i3 * 64 + sub * 8];
        float m0 = (p0 < s1) ? 1.f : 0.f;
        float m1 = (p1 < s1) ? 1.f : 0.f;
        float m2 = (p2 < s1) ? 1.f : 0.f;
        float m3 = (p3 < s1) ? 1.f : 0.f;
        ACC8(r0, m0);
        ACC8(r1, m1);
        ACC8(r2, m2);
        ACC8(r3, m3);
        for (int k = s0 + 32 + g; k < s1; k += 8) {  // rare (deg>32)
            int iv = csr[k];
            float4 rv = *(const float4*)&hh[(size_t)iv * 64 + sub * 8];
            ACC8(rv, 1.f);
        }
    }

#pragma unroll
    for (int j = 0; j < 8; ++j) {
        acc[j] += __shfl_xor(acc[j], 8, 64);
        acc[j] += __shfl_xor(acc[j], 16, 64);
        acc[j] += __shfl_xor(acc[j], 32, 64);
    }

    if (g == 0) {
        float4 sr = *(const float4*)&hh[(size_t)node * 64 + sub * 8];
        const __half2* sh = (const __half2*)&sr;
        float di = dinv[node];
        float2 f0 = __half22float2(sh[0]);
        float2 f1 = __half22float2(sh[1]);
        float2 f2 = __half22float2(sh[2]);
        float2 f3 = __half22float2(sh[3]);
        float o0 = (acc[0] + f0.x) * di;
        float o1 = (acc[1] + f0.y) * di;
        float o2 = (acc[2] + f1.x) * di;
        float o3 = (acc[3] + f1.y) * di;
        float o4 = (acc[4] + f2.x) * di;
        float o5 = (acc[5] + f2.y) * di;
        float o6 = (acc[6] + f3.x) * di;
        float o7 = (acc[7] + f3.y) * di;
        *(float4*)&gout[(size_t)node * 64 + sub * 8] = make_float4(o0, o1, o2, o3);
        *(float4*)&gout[(size_t)node * 64 + sub * 8 + 4] = make_float4(o4, o5, o6, o7);
    }
}

// mu|sig GEMM + bias + elu + pool stage-1.
// P[row][0..63] = elu(g@Wmu + bmu), P[row][64..127] = elu(g@Wsig + bsig),
// staged in LDS (reusing wc) then column-reduced per graph segment with
// boundary-flush atomics into sums (mu at [0,4096), sig at [4096,8192)).
__global__ __launch_bounds__(256) void k_mm_pool(const float* __restrict__ g,
                                                 const float* __restrict__ Wmu,
                                                 const float* __restrict__ Wsig,
                                                 const float* __restrict__ bmu,
                                                 const float* __restrict__ bsig,
                                                 const int* __restrict__ batch,
                                                 float* __restrict__ sums, int n) {
    __shared__ float hs[64 * 68];
    __shared__ float wc[64 * 132];  // [k][0..63]=Wmu, [k][64..127]=Wsig; later P
    __shared__ int bs[64];
    const int tid = threadIdx.x;
    const int m0 = blockIdx.x * 64;
    const int j = tid & 15;
    const int i = tid >> 4;

    const float4* g4 = (const float4*)g;
    const float4* Wm4 = (const float4*)Wmu;
    const float4* Ws4 = (const float4*)Wsig;
    for (int idx = tid; idx < 64 * 16; idx += 256) {
        int row = idx >> 4, c4 = idx & 15;
        float4 v = make_float4(0.f, 0.f, 0.f, 0.f);
        if (m0 + row < n) v = g4[(size_t)(m0 + row) * 16 + c4];
        *(float4*)&hs[row * 68 + 4 * c4] = v;
        *(float4*)&wc[row * 132 + 4 * c4] = Wm4[(size_t)row * 16 + c4];
        *(float4*)&wc[row * 132 + 64 + 4 * c4] = Ws4[(size_t)row * 16 + c4];
    }
    if (tid < 64) bs[tid] = (m0 + tid < n) ? batch[m0 + tid] : -1;
    __syncthreads();

    float4 accm[4], accs[4];
#pragma unroll
    for (int r = 0; r < 4; ++r) {
        accm[r] = make_float4(0.f, 0.f, 0.f, 0.f);
        accs[r] = make_float4(0.f, 0.f, 0.f, 0.f);
    }

#pragma unroll 1   // dynamic: bounds LDS-read hoisting / VGPR pressure (R5 lesson)
    for (int k4 = 0; k4 < 16; ++k4) {
        float4 a[4];
#pragma unroll
        for (int r = 0; r < 4; ++r)
            a[r] = *(const float4*)&hs[(4 * i + r) * 68 + 4 * k4];
#pragma unroll
        for (int kc = 0; kc < 4; ++kc) {
            float4 bm = *(const float4*)&wc[(4 * k4 + kc) * 132 + 4 * j];
            float4 bsv = *(const float4*)&wc[(4 * k4 + kc) * 132 + 64 + 4 * j];
#pragma unroll
            for (int r = 0; r < 4; ++r) {
                float av = (&a[r].x)[kc];
                accm[r].x = fmaf(av, bm.x, accm[r].x);
                accm[r].y = fmaf(av, bm.y, accm[r].y);
                accm[r].z = fmaf(av, bm.z, accm[r].z);
                accm[r].w = fmaf(av, bm.w, accm[r].w);
                accs[r].x = fmaf(av, bsv.x, accs[r].x);
                accs[r].y = fmaf(av, bsv.y, accs[r].y);
                accs[r].z = fmaf(av, bsv.z, accs[r].z);
                accs[r].w = fmaf(av, bsv.w, accs[r].w);
            }
        }
    }

    float4 bm = ((const float4*)bmu)[j];
    float4 bg = ((const float4*)bsig)[j];
    __syncthreads();  // all weight reads done before overwriting wc with P

#pragma unroll
    for (int r = 0; r < 4; ++r) {
        int row = 4 * i + r;
        float4 m = accm[r], s = accs[r];
        m.x = elu1(m.x + bm.x);
        m.y = elu1(m.y + bm.y);
        m.z = elu1(m.z + bm.z);
        m.w = elu1(m.w + bm.w);
        s.x = elu1(s.x + bg.x);
        s.y = elu1(s.y + bg.y);
        s.z = elu1(s.z + bg.z);
        s.w = elu1(s.w + bg.w);
        *(float4*)&wc[row * 132 + 4 * j] = m;
        *(float4*)&wc[row * 132 + 64 + 4 * j] = s;
    }
    __syncthreads();

    // Pool: thread (d, seg) reduces column d over rows [seg*32, seg*32+32),
    // flushing at graph boundaries (batch sorted).
    int d = tid & 127, seg = tid >> 7;
    int base = (d < 64) ? d : (64 * 64 - 64 + d);  // mu: g*64+d, sig: 4096+g*64+(d-64)
    float acc = 0.f;
    int gcur = -1;
    int r0 = seg * 32;
    for (int r = r0; r < r0 + 32; ++r) {
        int gb = bs[r];
        if (gb < 0) break;
        float v = wc[r * 132 + d];
        if (gb != gcur) {
            if (gcur >= 0) atomicAdd(&sums[base + gcur * 64], acc);
            acc = 0.f;
            gcur = gb;
        }
        acc += v;
    }
    if (gcur >= 0) atomicAdd(&sums[base + gcur * 64], acc);
}

// Pool stage 2: one thread per output element; cnt via binary search.
__global__ void k_pool_final(const float* __restrict__ sums,
                             const int* __restrict__ batch,
                             float* __restrict__ out, int n) {
    int i = blockIdx.x * blockDim.x + threadIdx.x;
    if (i >= 2 * N_GRAPHS * ZDIM) return;
    int g = (i >> 6) & 63;
    int lo = 0, hi = n;
    while (lo < hi) { int m = (lo + hi) >> 1; if (batch[m] < g) lo = m + 1; else hi = m; }
    int s = lo;
    lo = s; hi = n;
    while (lo < hi) { int m = (lo + hi) >> 1; if (batch[m] < g + 1) lo = m + 1; else hi = m; }
    float c = fmaxf((float)(lo - s), 1.0f);
    out[i] = sums[i] / c;
}

extern "C" void kernel_launch(void* const* d_in, const int* in_sizes, int n_in,
                              void* d_out, int out_size, void* d_ws, size_t ws_size,
                              hipStream_t stream) {
    const float* x    = (const float*)d_in[0];
    const int*   ei   = (const int*)d_in[1];
    const int*   batch= (const int*)d_in[2];
    // d_in[3] = num_graphs (scalar, known 64)
    const float* W1   = (const float*)d_in[4];
    const float* b1   = (const float*)d_in[5];
    const float* Wmu  = (const float*)d_in[6];
    const float* bmu  = (const float*)d_in[7];
    const float* Wsig = (const float*)d_in[8];
    const float* bsig = (const float*)d_in[9];
    float* out = (float*)d_out;

    const int n = in_sizes[0] / IN_DIM;   // 50000
    const int E = in_sizes[1] / 2;        // 800000
    const int* src = ei;
    const int* dst = ei + E;
    const int NSB = (n + SCAN_B - 1) / SCAN_B;  // scan blocks (49)

    float* ws = (float*)d_ws;
    size_t off_w = 0;
    int*   kc   = (int*)(ws + off_w); off_w += 50048;
    float* sums = ws + off_w; off_w += 8192;   // contiguous with kc: one memset
    float* dinv = ws + off_w; off_w += 50048;
    int*   offs = (int*)(ws + off_w); off_w += 50056;
    int*   bsum = (int*)(ws + off_w); off_w += 64;
    int*   rank = (int*)(ws + off_w); off_w += 800000;
    int*   csr  = (int*)(ws + off_w); off_w += 800000;
    off_w = (off_w + 15) & ~(size_t)15;
    const size_t BIG = (size_t)n * 64;
    __half* ts1h = (__half*)(ws + off_w); off_w += BIG / 2;  // fp16 (x@W1)*dinv
    __half* hh   = (__half*)(ws + off_w); off_w += BIG / 2;  // fp16 dinv*elu(layer1)
    float*  gbuf = ws + off_w; off_w += BIG;                 // f32 g = S*h

    const int gE  = (E + 255) / 256;
    const int gNW = (n + 3) / 4;      // one wave per node
    const int NB  = (n + 63) / 64;    // 64-node GEMM tiles

    // CSR build + normalization (kc+sums zeroed in ONE contiguous memset)
    hipMemsetAsync(kc, 0, (50048 + 8192) * sizeof(int), stream);
    k_count<<<gE, 256, 0, stream>>>(dst, kc, rank, E);
    k_scan1<<<NSB, SCAN_B, 0, stream>>>(kc, bsum, n);
    k_scan3<<<NSB, SCAN_B, 0, stream>>>(kc, bsum, offs, dinv, n, NSB);
    k_fill<<<gE, 256, 0, stream>>>(src, dst, rank, offs, csr, E);

    // layer 1: ts1h = fp16((x@W1)*dinv); hh = fp16(dinv*elu(S(xW1)+b1))
    k_mm1<<<NB, 256, 0, stream>>>(x, W1, dinv, ts1h, n);
    k_gather_hh<<<gNW, 256, 0, stream>>>(offs, csr, dinv, ts1h, b1, hh, n);

    // layers 2/3 shared gather: g = S*h (f32)
    k_gather_g<<<gNW, 256, 0, stream>>>(offs, csr, dinv, hh, gbuf, n);

    // mu|sig GEMM + bias + elu + fused pool stage-1
    k_mm_pool<<<NB, 256, 0, stream>>>(gbuf, Wmu, Wsig, bmu, bsig, batch, sums, n);
    k_pool_final<<<(2 * N_GRAPHS * ZDIM + 255) / 256, 256, 0, stream>>>(sums, batch, out, n);
}